// Round 7
// baseline (143.602 us; speedup 1.0000x reference)
//
#include <hip/hip_runtime.h>
#include <hip/hip_bf16.h>

#define R_RES 384
#define S_SEQ 128
#define CM 256
#define CC 32
#define CZ 128

typedef __attribute__((ext_vector_type(8))) short bf16x8;
typedef __attribute__((ext_vector_type(4))) float f32x4;
typedef __attribute__((ext_vector_type(16))) float f32x16;
typedef __attribute__((ext_vector_type(4))) int i32x4;

__device__ __forceinline__ short tobf16(float f) {
    union { __hip_bfloat16 h; short s; } u;
    u.h = __float2bfloat16(f);
    return u.s;
}

// ---------------- kernel 0a: w_out (1024,128) f32 -> wbTf fragment-tiled bf16 ----------------
// wbTf[(fz*64 + ks16)*64 + lane][8]: z = fz*32 + (lane&31), k = ks16*16 + (lane>>5)*8 + j
__global__ void k_transpose_wout(const float* __restrict__ w_out, short* __restrict__ wbTf) {
    __shared__ float t[64][65];
    int k0 = blockIdx.x * 64;   // 16 blocks over k=1024
    int z0 = blockIdx.y * 64;   // 2 blocks over z=128
    int tid = threadIdx.x;
    int c = tid & 63, rg = tid >> 6;
#pragma unroll
    for (int rr = 0; rr < 16; ++rr) {
        int kk = rg * 16 + rr;
        t[kk][c] = w_out[(size_t)(k0 + kk) * CZ + z0 + c];
    }
    __syncthreads();
#pragma unroll
    for (int l = 0; l < 2; ++l) {
        int id = l * 256 + tid;
        int f = id >> 6;               // 0..7
        int ksl = f >> 1, fzl = f & 1;
        int ln = id & 63;
        int zl = fzl * 32 + (ln & 31);
        int kl = ksl * 16 + (ln >> 5) * 8;
        bf16x8 pk;
#pragma unroll
        for (int j = 0; j < 8; ++j) pk[j] = tobf16(t[kl + j][zl]);
        size_t fz = blockIdx.y * 2 + fzl;
        size_t ks16 = blockIdx.x * 4 + ksl;
        *(bf16x8*)(wbTf + ((fz * 64 + ks16) * 64 + ln) * 8) = pk;
    }
}

// ---------------- kernel 0b: pack w1|w2 (256,32) -> wcT (64,256) bf16 ----------------
__global__ void k_pack_w12(const float* __restrict__ w1, const float* __restrict__ w2,
                           short* __restrict__ wcT) {
    int idx = blockIdx.x * 256 + threadIdx.x;
    int k = idx >> 6, n = idx & 63;
    float v = (n < 32) ? w1[k * CC + n] : w2[k * CC + (n - 32)];
    wcT[n * CM + k] = tobf16(v);
}

// ---------------- kernel 1: LayerNorm + projections -> aTf, bTf fragment-tiled bf16 ----------------
// aTf frag(fm16, ks32)[lane][8]: m = fm16*16 + (lane&15), s = ks32*32 + (lane>>4)*8 + j
__global__ __launch_bounds__(256) void k_ln_proj(
    const float* __restrict__ M, const float* __restrict__ ln_g, const float* __restrict__ ln_b,
    const float* __restrict__ b1, const float* __restrict__ b2,
    const short* __restrict__ wcT, short* __restrict__ aTf, short* __restrict__ bTf) {
    __shared__ short mnb[64 * 256];      // [s_loc][k] bf16, XOR-swizzled, 32 KB
    __shared__ short ab_s[2][32 * 72];   // [x][s_loc] stride-72 transpose buffers
    int r = blockIdx.x >> 1;
    int s0 = (blockIdx.x & 1) * 64;
    int tid = threadIdx.x, lane = tid & 63, w = tid >> 6;
    int g = lane >> 4, r16 = lane & 15;
    float4 gv = *(const float4*)(ln_g + lane * 4);
    float4 bv = *(const float4*)(ln_b + lane * 4);
    for (int it = 0; it < 16; ++it) {
        int sl = it * 4 + w;
        float4 v = *(const float4*)(M + ((size_t)(s0 + sl) * R_RES + r) * CM + lane * 4);
        float sum = v.x + v.y + v.z + v.w;
        float sq = v.x * v.x + v.y * v.y + v.z * v.z + v.w * v.w;
#pragma unroll
        for (int off = 32; off; off >>= 1) {
            sum += __shfl_xor(sum, off);
            sq  += __shfl_xor(sq, off);
        }
        float mu = sum * (1.0f / 256.0f);
        float var = sq * (1.0f / 256.0f) - mu * mu;
        float rstd = rsqrtf(var + 1e-5f);
        short4 mnp;
        mnp.x = tobf16((v.x - mu) * rstd * gv.x + bv.x);
        mnp.y = tobf16((v.y - mu) * rstd * gv.y + bv.y);
        mnp.z = tobf16((v.z - mu) * rstd * gv.z + bv.z);
        mnp.w = tobf16((v.w - mu) * rstd * gv.w + bv.w);
        int byte = sl * 512 + lane * 8;
        byte ^= ((sl & 7) << 4);
        *(short4*)((char*)mnb + byte) = mnp;
    }
    __syncthreads();
    f32x4 acc[4] = {{0,0,0,0},{0,0,0,0},{0,0,0,0},{0,0,0,0}};
    int srow = w * 16 + r16;
#pragma unroll
    for (int ks = 0; ks < 8; ++ks) {
        int byte = srow * 512 + ks * 64 + g * 16;
        byte ^= ((srow & 7) << 4);
        bf16x8 af = *(const bf16x8*)((const char*)mnb + byte);
#pragma unroll
        for (int nt = 0; nt < 4; ++nt) {
            bf16x8 bf = *(const bf16x8*)(wcT + (nt * 16 + r16) * CM + ks * 32 + g * 8);
            acc[nt] = __builtin_amdgcn_mfma_f32_16x16x32_bf16(af, bf, acc[nt], 0, 0, 0);
        }
    }
#pragma unroll
    for (int nt = 0; nt < 4; ++nt) {
        int n = nt * 16 + r16;
        int x = n & 31, sel = n >> 5;
        float bias = sel ? b2[x] : b1[x];
#pragma unroll
        for (int rr = 0; rr < 4; ++rr) {
            int sl = w * 16 + g * 4 + rr;
            ab_s[sel][x * 72 + sl] = tobf16(acc[nt][rr] + bias);
        }
    }
    __syncthreads();
    // fragment-tiled write-out: fm16 = r*2 + fl, ks32 = (s0>>5) + kl
    int piece = tid >> 6;            // 0..3
    int fl = piece >> 1, kl = piece & 1;
    int ln = tid & 63;
    int x = fl * 16 + (ln & 15);
    int s_loc = kl * 32 + (ln >> 4) * 8;
    i32x4 va = *(const i32x4*)((const char*)ab_s[0] + (x * 72 + s_loc) * 2);
    i32x4 vb = *(const i32x4*)((const char*)ab_s[1] + (x * 72 + s_loc) * 2);
    size_t off = ((((size_t)r * 2 + fl) * 4 + (s0 >> 5) + kl) * 64 + ln) * 16;
    *(i32x4*)((char*)aTf + off) = va;
    *(i32x4*)((char*)bTf + off) = vb;
}

// ---------------- kernel 2: fused outer-product + w_out contraction ----------------
// grid (48 bj, 48 bi), 1024 thr (16 waves), O-tile 256x256 (8res x 8res), LDS 128 KB.
// stage A[0,64K)+B[64K,128K) -> ph2 (wave 4x4) -> A2 64p x 1024k bf16 [0,128K)
// -> ph4 32x32x16 (pd2 x zq4 x kh2) -> Pp f32 2x32KB [0,64K) -> coalesced reduce.
__global__ __launch_bounds__(1024, 4) void k_opm(
    const short* __restrict__ aTf, const short* __restrict__ bTf,
    const short* __restrict__ wbTf, const float* __restrict__ b_out,
    float* __restrict__ out) {
    __shared__ __align__(16) char smem[131072];
    int tid = threadIdx.x, lane = tid & 63, w = tid >> 6;   // w 0..15
    int g = lane >> 4, r16 = lane & 15;
    int l32 = lane & 31, h = lane >> 5;
    int wm = w & 3, wn = w >> 2;            // ph2 wave grid: 4(m) x 4(n)
    int bj = blockIdx.x, bi = blockIdx.y;

    // ---- stage A-strip and B-strip (64 KB each), verbatim fragment-tiled regions
    const char* gA = (const char*)aTf + (size_t)bi * 65536;
    const char* gB = (const char*)bTf + (size_t)bj * 65536;
#pragma unroll
    for (int it = 0; it < 4; ++it) {
        int q = it * 16384 + tid * 16;
        __builtin_amdgcn_global_load_lds(
            (const __attribute__((address_space(1))) void*)(gA + q),
            (__attribute__((address_space(3))) void*)(smem + q), 16, 0, 0);
        __builtin_amdgcn_global_load_lds(
            (const __attribute__((address_space(1))) void*)(gB + q),
            (__attribute__((address_space(3))) void*)(smem + 65536 + q), 16, 0, 0);
    }
    __syncthreads();

    // ---- ph2: O[256x256]; acc[mi][ni]: m = wm*64+mi*16+r16, n = wn*64+ni*16+g*4+rr
    f32x4 acc[4][4] = {};
#pragma unroll
    for (int ks = 0; ks < 4; ++ks) {
        bf16x8 bf[4], af[4];
#pragma unroll
        for (int ni = 0; ni < 4; ++ni)
            bf[ni] = *(const bf16x8*)(smem + 65536 + (((wn * 4 + ni) * 4 + ks) * 64 + lane) * 16);
#pragma unroll
        for (int mi = 0; mi < 4; ++mi)
            af[mi] = *(const bf16x8*)(smem + (((wm * 4 + mi) * 4 + ks) * 64 + lane) * 16);
        __builtin_amdgcn_s_setprio(1);
#pragma unroll
        for (int mi = 0; mi < 4; ++mi)
#pragma unroll
            for (int ni = 0; ni < 4; ++ni)
                acc[mi][ni] = __builtin_amdgcn_mfma_f32_16x16x32_bf16(bf[ni], af[mi], acc[mi][ni], 0, 0, 0);
        __builtin_amdgcn_s_setprio(0);
    }
    __syncthreads();   // A/B reads done -> smem becomes A2 (128 KB)

    // ---- ph3: O -> A2 bf16 [p = i*8+j][k = x*32+y], dual-XOR swizzle
#pragma unroll
    for (int mi = 0; mi < 4; ++mi)
#pragma unroll
        for (int ni = 0; ni < 4; ++ni) {
            int m = wm * 64 + mi * 16 + r16;
            int nb = wn * 64 + ni * 16 + g * 4;
            int i = m >> 5, x = m & 31;
            int j = nb >> 5, y0 = nb & 31;
            int p = i * 8 + j;
            int byte = (p * 2048 + x * 64 + y0 * 2) ^ (((p & 7) ^ (x & 7)) << 4);
            short4 pk;
            pk.x = tobf16(acc[mi][ni][0]);
            pk.y = tobf16(acc[mi][ni][1]);
            pk.z = tobf16(acc[mi][ni][2]);
            pk.w = tobf16(acc[mi][ni][3]);
            *(short4*)(smem + byte) = pk;
        }
    __syncthreads();

    // ---- ph4: 32x32x16; wave (kh = w&1, zq = (w>>1)&3, pd = w>>3)
    int kh = w & 1, zq = (w >> 1) & 3, pd = w >> 3;
    f32x16 c2a = {0,0,0,0,0,0,0,0,0,0,0,0,0,0,0,0};
    f32x16 c2b = {0,0,0,0,0,0,0,0,0,0,0,0,0,0,0,0};
    const short* wbase = wbTf + (size_t)((zq * 64 + kh * 32) * 64) * 8;
    int pbase = pd * 32 + l32;
#pragma unroll 8
    for (int ks = 0; ks < 32; ++ks) {
        int x = kh * 16 + (ks >> 1);
        int byte = (pbase * 2048 + kh * 1024 + ks * 32 + h * 16)
                   ^ ((((l32 & 7) ^ (x & 7))) << 4);
        bf16x8 a2f = *(const bf16x8*)(smem + byte);
        bf16x8 wbf = *(const bf16x8*)(wbase + (ks * 64 + lane) * 8);
        if (ks & 1) c2b = __builtin_amdgcn_mfma_f32_32x32x16_bf16(a2f, wbf, c2b, 0, 0, 0);
        else        c2a = __builtin_amdgcn_mfma_f32_32x32x16_bf16(a2f, wbf, c2a, 0, 0, 0);
    }
    f32x16 c2 = c2a + c2b;
    __syncthreads();   // all A2 reads done -> [0,64K) becomes Pp

    // ---- Pp write: [kh][p 64][z 128] f32, addr ^ ((p&1)<<4); conflict-free stores
#pragma unroll
    for (int q = 0; q < 4; ++q)
#pragma unroll
        for (int rr = 0; rr < 4; ++rr) {
            int prow = pd * 32 + q * 8 + h * 4 + rr;
            int zz = zq * 32 + l32;
            int byte = (kh * 32768 + prow * 512 + zz * 4) ^ ((prow & 1) << 4);
            *(float*)(smem + byte) = c2[q * 4 + rr];
        }
    __syncthreads();

    // ---- reduce kh-halves + coalesced f32x4 stores
    {
        int p = tid >> 4;              // 0..63
        int zo = (tid & 15) * 8;       // 0..120
        int sw = (p & 1) << 4;
        int base = p * 512 + zo * 4;
        f32x4 u0 = *(const f32x4*)(smem + ((base) ^ sw));
        f32x4 u1 = *(const f32x4*)(smem + ((base + 16) ^ sw));
        f32x4 v0 = *(const f32x4*)(smem + ((base + 32768) ^ sw));
        f32x4 v1 = *(const f32x4*)(smem + ((base + 16 + 32768) ^ sw));
        float4 bo0 = *(const float4*)(b_out + zo);
        float4 bo1 = *(const float4*)(b_out + zo + 4);
        f32x4 r0, r1;
        r0[0] = (u0[0] + v0[0] + bo0.x) * (1.0f / 128.0f);
        r0[1] = (u0[1] + v0[1] + bo0.y) * (1.0f / 128.0f);
        r0[2] = (u0[2] + v0[2] + bo0.z) * (1.0f / 128.0f);
        r0[3] = (u0[3] + v0[3] + bo0.w) * (1.0f / 128.0f);
        r1[0] = (u1[0] + v1[0] + bo1.x) * (1.0f / 128.0f);
        r1[1] = (u1[1] + v1[1] + bo1.y) * (1.0f / 128.0f);
        r1[2] = (u1[2] + v1[2] + bo1.z) * (1.0f / 128.0f);
        r1[3] = (u1[3] + v1[3] + bo1.w) * (1.0f / 128.0f);
        int ig = bi * 8 + (p >> 3);
        int jg = bj * 8 + (p & 7);
        float* po = out + ((size_t)ig * R_RES + jg) * CZ + zo;
        *(f32x4*)(po) = r0;
        *(f32x4*)(po + 4) = r1;
    }
}

extern "C" void kernel_launch(void* const* d_in, const int* in_sizes, int n_in,
                              void* d_out, int out_size, void* d_ws, size_t ws_size,
                              hipStream_t stream) {
    const float* M     = (const float*)d_in[0];
    const float* ln_g  = (const float*)d_in[1];
    const float* ln_b  = (const float*)d_in[2];
    const float* w1    = (const float*)d_in[3];
    const float* b1    = (const float*)d_in[4];
    const float* w2    = (const float*)d_in[5];
    const float* b2    = (const float*)d_in[6];
    const float* w_out = (const float*)d_in[7];
    const float* b_out = (const float*)d_in[8];
    float* out = (float*)d_out;

    short* aTf  = (short*)d_ws;             // 12288 x 128 bf16, fragment-tiled
    short* bTf  = aTf + 12288 * 128;        // 12288 x 128 bf16, fragment-tiled
    short* wbTf = bTf + 12288 * 128;        // 128 x 1024 bf16, fragment-tiled
    short* wcT  = wbTf + 128 * 1024;        // 64 x 256 bf16

    k_transpose_wout<<<dim3(16, 2), 256, 0, stream>>>(w_out, wbTf);
    k_pack_w12<<<64, 256, 0, stream>>>(w1, w2, wcT);
    k_ln_proj<<<768, 256, 0, stream>>>(M, ln_g, ln_b, b1, b2, wcT, aTf, bTf);
    k_opm<<<dim3(48, 48), 1024, 0, stream>>>(aTf, bTf, wbTf, b_out, out);
}

// Round 8
// 128.050 us; speedup vs baseline: 1.1215x; 1.1215x over previous
//
#include <hip/hip_runtime.h>
#include <hip/hip_bf16.h>

#define R_RES 384
#define S_SEQ 128
#define CM 256
#define CC 32
#define CZ 128

typedef __attribute__((ext_vector_type(8))) short bf16x8;
typedef __attribute__((ext_vector_type(4))) float f32x4;
typedef __attribute__((ext_vector_type(16))) float f32x16;
typedef __attribute__((ext_vector_type(4))) int i32x4;

__device__ __forceinline__ short tobf16(float f) {
    union { __hip_bfloat16 h; short s; } u;
    u.h = __float2bfloat16(f);
    return u.s;
}

// lgkm-only barrier: LDS visibility without draining outstanding global loads
__device__ __forceinline__ void lgkm_barrier() {
    asm volatile("s_waitcnt lgkmcnt(0)" ::: "memory");
    __builtin_amdgcn_s_barrier();
    __builtin_amdgcn_sched_barrier(0);
}

// ---------------- kernel 0a: w_out (1024,128) f32 -> wbTf fragment-tiled bf16 ----------------
// wbTf[(fz*64 + ks16)*64 + lane][8]: z = fz*32 + (lane&31), k = ks16*16 + (lane>>5)*8 + j
__global__ void k_transpose_wout(const float* __restrict__ w_out, short* __restrict__ wbTf) {
    __shared__ float t[64][65];
    int k0 = blockIdx.x * 64;   // 16 blocks over k=1024
    int z0 = blockIdx.y * 64;   // 2 blocks over z=128
    int tid = threadIdx.x;
    int c = tid & 63, rg = tid >> 6;
#pragma unroll
    for (int rr = 0; rr < 16; ++rr) {
        int kk = rg * 16 + rr;
        t[kk][c] = w_out[(size_t)(k0 + kk) * CZ + z0 + c];
    }
    __syncthreads();
#pragma unroll
    for (int l = 0; l < 2; ++l) {
        int id = l * 256 + tid;
        int f = id >> 6;               // 0..7
        int ksl = f >> 1, fzl = f & 1;
        int ln = id & 63;
        int zl = fzl * 32 + (ln & 31);
        int kl = ksl * 16 + (ln >> 5) * 8;
        bf16x8 pk;
#pragma unroll
        for (int j = 0; j < 8; ++j) pk[j] = tobf16(t[kl + j][zl]);
        size_t fz = blockIdx.y * 2 + fzl;
        size_t ks16 = blockIdx.x * 4 + ksl;
        *(bf16x8*)(wbTf + ((fz * 64 + ks16) * 64 + ln) * 8) = pk;
    }
}

// ---------------- kernel 0b: pack w1|w2 (256,32) -> wcT (64,256) bf16 ----------------
__global__ void k_pack_w12(const float* __restrict__ w1, const float* __restrict__ w2,
                           short* __restrict__ wcT) {
    int idx = blockIdx.x * 256 + threadIdx.x;
    int k = idx >> 6, n = idx & 63;
    float v = (n < 32) ? w1[k * CC + n] : w2[k * CC + (n - 32)];
    wcT[n * CM + k] = tobf16(v);
}

// ---------------- kernel 1: LayerNorm + projections -> aTf, bTf fragment-tiled bf16 ----------------
// aTf frag(fm16, ks32)[lane][8]: m = fm16*16 + (lane&15), s = ks32*32 + (lane>>4)*8 + j
__global__ __launch_bounds__(256) void k_ln_proj(
    const float* __restrict__ M, const float* __restrict__ ln_g, const float* __restrict__ ln_b,
    const float* __restrict__ b1, const float* __restrict__ b2,
    const short* __restrict__ wcT, short* __restrict__ aTf, short* __restrict__ bTf) {
    __shared__ short mnb[64 * 256];      // [s_loc][k] bf16, XOR-swizzled, 32 KB
    __shared__ short ab_s[2][32 * 72];   // [x][s_loc] stride-72 transpose buffers
    int r = blockIdx.x >> 1;
    int s0 = (blockIdx.x & 1) * 64;
    int tid = threadIdx.x, lane = tid & 63, w = tid >> 6;
    int g = lane >> 4, r16 = lane & 15;
    float4 gv = *(const float4*)(ln_g + lane * 4);
    float4 bv = *(const float4*)(ln_b + lane * 4);
    for (int it = 0; it < 16; ++it) {
        int sl = it * 4 + w;
        float4 v = *(const float4*)(M + ((size_t)(s0 + sl) * R_RES + r) * CM + lane * 4);
        float sum = v.x + v.y + v.z + v.w;
        float sq = v.x * v.x + v.y * v.y + v.z * v.z + v.w * v.w;
#pragma unroll
        for (int off = 32; off; off >>= 1) {
            sum += __shfl_xor(sum, off);
            sq  += __shfl_xor(sq, off);
        }
        float mu = sum * (1.0f / 256.0f);
        float var = sq * (1.0f / 256.0f) - mu * mu;
        float rstd = rsqrtf(var + 1e-5f);
        short4 mnp;
        mnp.x = tobf16((v.x - mu) * rstd * gv.x + bv.x);
        mnp.y = tobf16((v.y - mu) * rstd * gv.y + bv.y);
        mnp.z = tobf16((v.z - mu) * rstd * gv.z + bv.z);
        mnp.w = tobf16((v.w - mu) * rstd * gv.w + bv.w);
        int byte = sl * 512 + lane * 8;
        byte ^= ((sl & 7) << 4);
        *(short4*)((char*)mnb + byte) = mnp;
    }
    __syncthreads();
    f32x4 acc[4] = {{0,0,0,0},{0,0,0,0},{0,0,0,0},{0,0,0,0}};
    int srow = w * 16 + r16;
#pragma unroll
    for (int ks = 0; ks < 8; ++ks) {
        int byte = srow * 512 + ks * 64 + g * 16;
        byte ^= ((srow & 7) << 4);
        bf16x8 af = *(const bf16x8*)((const char*)mnb + byte);
#pragma unroll
        for (int nt = 0; nt < 4; ++nt) {
            bf16x8 bf = *(const bf16x8*)(wcT + (nt * 16 + r16) * CM + ks * 32 + g * 8);
            acc[nt] = __builtin_amdgcn_mfma_f32_16x16x32_bf16(af, bf, acc[nt], 0, 0, 0);
        }
    }
#pragma unroll
    for (int nt = 0; nt < 4; ++nt) {
        int n = nt * 16 + r16;
        int x = n & 31, sel = n >> 5;
        float bias = sel ? b2[x] : b1[x];
#pragma unroll
        for (int rr = 0; rr < 4; ++rr) {
            int sl = w * 16 + g * 4 + rr;
            ab_s[sel][x * 72 + sl] = tobf16(acc[nt][rr] + bias);
        }
    }
    __syncthreads();
    // fragment-tiled write-out: fm16 = r*2 + fl, ks32 = (s0>>5) + kl
    int piece = tid >> 6;            // 0..3
    int fl = piece >> 1, kl = piece & 1;
    int ln = tid & 63;
    int x = fl * 16 + (ln & 15);
    int s_loc = kl * 32 + (ln >> 4) * 8;
    i32x4 va = *(const i32x4*)((const char*)ab_s[0] + (x * 72 + s_loc) * 2);
    i32x4 vb = *(const i32x4*)((const char*)ab_s[1] + (x * 72 + s_loc) * 2);
    size_t off = ((((size_t)r * 2 + fl) * 4 + (s0 >> 5) + kl) * 64 + ln) * 16;
    *(i32x4*)((char*)aTf + off) = va;
    *(i32x4*)((char*)bTf + off) = vb;
}

// ---------------- kernel 2: fused outer-product + w_out contraction ----------------
// grid (96 bj, 48 bi), 512 thr (8 waves), O-tile 256(i:8res) x 128(j:4res), LDS 64 KB.
// ph2: wave grid 8m x 1n -> A dup-free from L2, B from LDS. ph4: 32x32x16 (kh x zq),
// rolling wbf prefetch across lgkm-only barriers. 2 blocks/CU.
__global__ __launch_bounds__(512, 4) void k_opm(
    const short* __restrict__ aTf, const short* __restrict__ bTf,
    const short* __restrict__ wbTf, const float* __restrict__ b_out,
    float* __restrict__ out) {
    __shared__ __align__(16) char smem[65536];
    int tid = threadIdx.x, lane = tid & 63, w = tid >> 6;
    int g = lane >> 4, r16 = lane & 15;
    int l32 = lane & 31, h = lane >> 5;
    int wm = w;                             // ph2 wave grid: 8(m) x 1(n)
    int bj = blockIdx.x, bi = blockIdx.y;

    // ---- stage B-frags (32 KB, verbatim bTf[bj] region) into smem[0,32K)
    const char* gB = (const char*)bTf + (size_t)bj * 32768;
#pragma unroll
    for (int it = 0; it < 4; ++it) {
        int q = it * 8192 + tid * 16;
        __builtin_amdgcn_global_load_lds(
            (const __attribute__((address_space(1))) void*)(gB + q),
            (__attribute__((address_space(3))) void*)(smem + q), 16, 0, 0);
    }
    // pre-issue af for ks=0 (independent of LDS staging)
    const char* gA = (const char*)aTf + (size_t)bi * 65536;
    bf16x8 afc0 = *(const bf16x8*)(gA + (((wm * 2 + 0) * 4 + 0) * 64 + lane) * 16);
    bf16x8 afc1 = *(const bf16x8*)(gA + (((wm * 2 + 1) * 4 + 0) * 64 + lane) * 16);
    __syncthreads();   // drains staging (vmcnt) + af preload

    // ---- ph2: O[256x128]; acc[mi][ni]: m = wm*32+mi*16+r16, n = ni*16+g*4+rr
    f32x4 acc[2][8] = {};
#pragma unroll
    for (int ks = 0; ks < 4; ++ks) {
        int ksn = (ks + 1) & 3;
        bf16x8 bf[8];
#pragma unroll
        for (int ni = 0; ni < 4; ++ni)
            bf[ni] = *(const bf16x8*)(smem + ((ni * 4 + ks) * 64 + lane) * 16);
        bf16x8 afn0 = *(const bf16x8*)(gA + (((wm * 2 + 0) * 4 + ksn) * 64 + lane) * 16);
        bf16x8 afn1 = *(const bf16x8*)(gA + (((wm * 2 + 1) * 4 + ksn) * 64 + lane) * 16);
        __builtin_amdgcn_s_setprio(1);
#pragma unroll
        for (int ni = 0; ni < 4; ++ni) {
            acc[0][ni] = __builtin_amdgcn_mfma_f32_16x16x32_bf16(bf[ni], afc0, acc[0][ni], 0, 0, 0);
            acc[1][ni] = __builtin_amdgcn_mfma_f32_16x16x32_bf16(bf[ni], afc1, acc[1][ni], 0, 0, 0);
        }
        __builtin_amdgcn_s_setprio(0);
#pragma unroll
        for (int ni = 4; ni < 8; ++ni)
            bf[ni] = *(const bf16x8*)(smem + ((ni * 4 + ks) * 64 + lane) * 16);
        __builtin_amdgcn_s_setprio(1);
#pragma unroll
        for (int ni = 4; ni < 8; ++ni) {
            acc[0][ni] = __builtin_amdgcn_mfma_f32_16x16x32_bf16(bf[ni], afc0, acc[0][ni], 0, 0, 0);
            acc[1][ni] = __builtin_amdgcn_mfma_f32_16x16x32_bf16(bf[ni], afc1, acc[1][ni], 0, 0, 0);
        }
        __builtin_amdgcn_s_setprio(0);
        afc0 = afn0;
        afc1 = afn1;
    }
    lgkm_barrier();   // all B ds_reads done -> smem becomes A2 (64 KB)

    // ---- ph3: O -> A2 bf16 [p = i*4+j][k = x*32+y], dual-XOR swizzle
#pragma unroll
    for (int mi = 0; mi < 2; ++mi)
#pragma unroll
        for (int ni = 0; ni < 8; ++ni) {
            int x = mi * 16 + r16;              // i = wm
            int nb = ni * 16 + g * 4;
            int j = nb >> 5, y0 = nb & 31;
            int p = wm * 4 + j;
            int byte = (p * 2048 + x * 64 + y0 * 2) ^ (((p & 7) ^ (x & 7)) << 4);
            short4 pk;
            pk.x = tobf16(acc[mi][ni][0]);
            pk.y = tobf16(acc[mi][ni][1]);
            pk.z = tobf16(acc[mi][ni][2]);
            pk.w = tobf16(acc[mi][ni][3]);
            *(short4*)(smem + byte) = pk;
        }

    // pre-issue first 4 wbf fragments for ph4 (global; survive the lgkm barrier)
    int kh = w & 1, zq = w >> 1;
    const short* wbase = wbTf + (size_t)((zq * 64 + kh * 32) * 64) * 8;
    bf16x8 wpf[4];
#pragma unroll
    for (int u = 0; u < 4; ++u)
        wpf[u] = *(const bf16x8*)(wbase + (u * 64 + lane) * 8);
    lgkm_barrier();   // A2 visible; wbf loads still in flight

    // ---- ph4: 32x32x16; wave (kh, zq): [32p x 32z], k-half 512; rolling wbf prefetch
    f32x16 c2a = {0,0,0,0,0,0,0,0,0,0,0,0,0,0,0,0};
    f32x16 c2b = {0,0,0,0,0,0,0,0,0,0,0,0,0,0,0,0};
#pragma unroll
    for (int kq = 0; kq < 8; ++kq) {
        bf16x8 w0 = wpf[0], w1 = wpf[1], w2 = wpf[2], w3 = wpf[3];
        if (kq < 7) {
#pragma unroll
            for (int u = 0; u < 4; ++u)
                wpf[u] = *(const bf16x8*)(wbase + ((kq * 4 + 4 + u) * 64 + lane) * 8);
        }
        bf16x8 a2f[4];
#pragma unroll
        for (int u = 0; u < 4; ++u) {
            int ks = kq * 4 + u;
            int x = (kh * 32 + ks) >> 1;
            int byte = (l32 * 2048 + kh * 1024 + ks * 32 + h * 16)
                       ^ ((((l32 & 7) ^ (x & 7))) << 4);
            a2f[u] = *(const bf16x8*)(smem + byte);
        }
        __builtin_amdgcn_s_setprio(1);
        c2a = __builtin_amdgcn_mfma_f32_32x32x16_bf16(a2f[0], w0, c2a, 0, 0, 0);
        c2b = __builtin_amdgcn_mfma_f32_32x32x16_bf16(a2f[1], w1, c2b, 0, 0, 0);
        c2a = __builtin_amdgcn_mfma_f32_32x32x16_bf16(a2f[2], w2, c2a, 0, 0, 0);
        c2b = __builtin_amdgcn_mfma_f32_32x32x16_bf16(a2f[3], w3, c2b, 0, 0, 0);
        __builtin_amdgcn_s_setprio(0);
    }
    f32x16 c2 = c2a + c2b;
    lgkm_barrier();   // all A2 reads done -> [0,32K) becomes Pp

    // ---- Pp write: slab (zq*2+kh) 4KB: [z' 32][p 32] f32, ^((z'&7)<<4)
#pragma unroll
    for (int q = 0; q < 4; ++q) {
        f32x4 v;
        v[0] = c2[q * 4 + 0]; v[1] = c2[q * 4 + 1];
        v[2] = c2[q * 4 + 2]; v[3] = c2[q * 4 + 3];
        int byte = ((zq * 2 + kh) * 4096 + l32 * 128 + q * 32 + h * 16) ^ ((l32 & 7) << 4);
        *(f32x4*)(smem + byte) = v;
    }
    lgkm_barrier();

    // ---- reduce kh-halves + coalesced store
    int z = tid & 127, zq2 = z >> 5, zp = z & 31;
    int pr0 = tid >> 7;
    float bo = b_out[z];
#pragma unroll
    for (int stp = 0; stp < 2; ++stp) {
        int prq = pr0 + stp * 4;                 // p-quad 0..7
        int base = zq2 * 8192 + zp * 128 + prq * 16;
        int sw = (zp & 7) << 4;
        f32x4 v0 = *(const f32x4*)(smem + (base ^ sw));
        f32x4 v1 = *(const f32x4*)(smem + ((base + 4096) ^ sw));
#pragma unroll
        for (int rr = 0; rr < 4; ++rr) {
            int p = prq * 4 + rr;
            int ig = bi * 8 + (p >> 2);
            int jg = bj * 4 + (p & 3);
            out[((size_t)ig * R_RES + jg) * CZ + z] = (v0[rr] + v1[rr] + bo) * (1.0f / 128.0f);
        }
    }
}

extern "C" void kernel_launch(void* const* d_in, const int* in_sizes, int n_in,
                              void* d_out, int out_size, void* d_ws, size_t ws_size,
                              hipStream_t stream) {
    const float* M     = (const float*)d_in[0];
    const float* ln_g  = (const float*)d_in[1];
    const float* ln_b  = (const float*)d_in[2];
    const float* w1    = (const float*)d_in[3];
    const float* b1    = (const float*)d_in[4];
    const float* w2    = (const float*)d_in[5];
    const float* b2    = (const float*)d_in[6];
    const float* w_out = (const float*)d_in[7];
    const float* b_out = (const float*)d_in[8];
    float* out = (float*)d_out;

    short* aTf  = (short*)d_ws;             // 12288 x 128 bf16, fragment-tiled
    short* bTf  = aTf + 12288 * 128;        // 12288 x 128 bf16, fragment-tiled
    short* wbTf = bTf + 12288 * 128;        // 128 x 1024 bf16, fragment-tiled
    short* wcT  = wbTf + 128 * 1024;        // 64 x 256 bf16

    k_transpose_wout<<<dim3(16, 2), 256, 0, stream>>>(w_out, wbTf);
    k_pack_w12<<<64, 256, 0, stream>>>(w1, w2, wcT);
    k_ln_proj<<<768, 256, 0, stream>>>(M, ln_g, ln_b, b1, b2, wcT, aTf, bTf);
    k_opm<<<dim3(96, 48), 512, 0, stream>>>(aTf, bTf, wbTf, b_out, out);
}